// Round 8
// baseline (477.960 us; speedup 1.0000x reference)
//
#include <hip/hip_runtime.h>
#include <math.h>

#define BB 32
#define NN 1024
#define FF 64
#define PP 128
#define KNN 16
#define H2 256  // 2P
#define F2 128  // 2F
#define KSEL 17
#define SVCAP 272

typedef float f32x4 __attribute__((ext_vector_type(4)));
typedef __bf16 bf16x8 __attribute__((ext_vector_type(8)));

__device__ __forceinline__ float gelu_fast(float x) {
    // x * sigmoid(2.3022115x + 0.1029438x^3); |err vs exact gelu| ~3e-4
    float s = x * x;
    float arg = x * fmaf(s, -0.1029438f, -2.3022115f);
    float e = __builtin_amdgcn_exp2f(arg);
    return x * __builtin_amdgcn_rcpf(1.0f + e);
}

// ------- Kernel A: set-based kNN (blocks 0..4095) + weight-frag prep (4096..4111) ---
__global__ __launch_bounds__(512, 8) void knn_prep(const float* __restrict__ points,
                                                   int* __restrict__ idx_out,
                                                   const float* __restrict__ W1,
                                                   const float* __restrict__ W2,
                                                   __bf16* __restrict__ Wcf,
                                                   __bf16* __restrict__ W2f) {
    if (blockIdx.x >= 4096) {
        // ---- prep path: fragment-swizzled Wcf (gq_gemm B) + W2f (fused B) ----
        int tid = (blockIdx.x - 4096) * 512 + threadIdx.x;   // 0..8191
        if (tid < 4096) {
            const int lane = tid & 63, quad = lane >> 4, l16 = lane & 15;
            const int kk = (tid >> 6) & 1, n_tile = tid >> 7;
            const int n = n_tile * 16 + l16;
            const int kb = kk * 32 + quad * 8;
            bf16x8 v;
#pragma unroll
            for (int j = 0; j < 8; ++j) {
                const int k = kb + j;
                float x = (n < 256) ? W1[k * 256 + n]
                                    : (W1[(64 + k) * 256 + (n - 256)] - W1[k * 256 + (n - 256)]);
                v[j] = (__bf16)x;
            }
            *(bf16x8*)(Wcf + (size_t)tid * 8) = v;
        } else {
            const int t2 = tid - 4096;
            const int lane = t2 & 63, quad = lane >> 4, l16 = lane & 15;
            const int nt = (t2 >> 6) & 7, kk8 = t2 >> 9;
            const int p = nt * 16 + l16;
            const int hb = kk8 * 32 + quad * 8;
            bf16x8 v;
#pragma unroll
            for (int j = 0; j < 8; ++j) v[j] = (__bf16)W2[(size_t)(hb + j) * PP + p];
            *(bf16x8*)(W2f + (size_t)t2 * 8) = v;
        }
        return;
    }

    __shared__ float4 pts[NN];
    __shared__ unsigned sv_val[8][SVCAP];
    __shared__ unsigned sv_idx[8][SVCAP];
    __shared__ unsigned tie_idx[8][64];

    const int t = threadIdx.x;
    const int w = t >> 6, lane = t & 63;
    const int b = blockIdx.x >> 7;
    const int q0 = (blockIdx.x & 127) * 8;
    const float* pb = points + (size_t)b * NN * 3;
    const unsigned long long lt = (1ull << lane) - 1ull;

    for (int i = t; i < NN; i += 512) {
        float x = pb[3 * i], y = pb[3 * i + 1], z = pb[3 * i + 2];
        float r = __fadd_rn(__fadd_rn(__fmul_rn(x, x), __fmul_rn(y, y)), __fmul_rn(z, z));
        pts[i] = make_float4(x, y, z, r);
    }
    __syncthreads();

    const int qn = q0 + w;
    const int gq = b * NN + qn;
    const float4 qp = pts[qn];

    float D[16];
#pragma unroll
    for (int j = 0; j < 16; ++j) {
        float4 c = pts[j * 64 + lane];
        float dot = __fadd_rn(__fadd_rn(__fmul_rn(qp.x, c.x), __fmul_rn(qp.y, c.y)),
                              __fmul_rn(qp.z, c.z));
        D[j] = __fadd_rn(__fadd_rn(__fsub_rn(qp.w, __fmul_rn(2.0f, dot)), c.w), 1e-5f);
    }

    float mnf = D[0];
#pragma unroll
    for (int j = 1; j < 16; ++j) mnf = fminf(mnf, D[j]);
    const unsigned mbits = __float_as_uint(mnf);

    unsigned T = 0;
#pragma unroll
    for (int bit = 31; bit >= 0; --bit) {
        unsigned cand = T | (1u << bit);
        int cnt = __popcll(__ballot(mbits < cand));
        if (cnt < KSEL) T = cand;
    }

    unsigned base = 0;
#pragma unroll
    for (int j = 0; j < 16; ++j) {
        unsigned vb = __float_as_uint(D[j]);
        bool keep = (vb <= T);
        unsigned long long m = __ballot(keep);
        if (keep) {
            unsigned pos = base + (unsigned)__popcll(m & lt);
            if (pos < SVCAP) { sv_val[w][pos] = vb; sv_idx[w][pos] = j * 64 + lane; }
        }
        base += (unsigned)__popcll(m);
    }
    unsigned C = base > SVCAP ? SVCAP : base;
    const int S = (int)((C + 63) >> 6);

    unsigned Ts = 0;
    if (S == 1) {
        unsigned xv0 = (lane < (int)C) ? sv_val[w][lane] : 0xFFFFFFFFu;
#pragma unroll
        for (int bit = 31; bit >= 0; --bit) {
            unsigned cand = Ts | (1u << bit);
            int cnt = __popcll(__ballot(xv0 < cand));
            if (cnt < KSEL) Ts = cand;
        }
    } else {
        for (int bit = 31; bit >= 0; --bit) {
            unsigned cand = Ts | (1u << bit);
            int cnt = 0;
            for (int s = 0; s < S; ++s) {
                int i = s * 64 + lane;
                unsigned vb = (i < (int)C) ? sv_val[w][i] : 0xFFFFFFFFu;
                cnt += __popcll(__ballot(vb < cand));
            }
            if (cnt < KSEL) Ts = cand;
        }
    }

    int L = 0;
    for (int s = 0; s < S; ++s) {
        int i = s * 64 + lane;
        unsigned vb = (i < (int)C) ? sv_val[w][i] : 0xFFFFFFFFu;
        L += __popcll(__ballot(vb < Ts));
    }
    const int need = KSEL - L;

    unsigned vmin_l = 0xFFFFFFFFu;
    for (int s = 0; s < S; ++s) {
        int i = s * 64 + lane;
        unsigned vb = (i < (int)C) ? sv_val[w][i] : 0xFFFFFFFFu;
        vmin_l = vmin_l < vb ? vmin_l : vb;
    }
#pragma unroll
    for (int off = 32; off >= 1; off >>= 1) {
        unsigned o2 = __shfl_xor(vmin_l, off, 64);
        vmin_l = vmin_l < o2 ? vmin_l : o2;
    }
    const unsigned Vmin = vmin_l;
    unsigned imin_l = 0xFFFFFFFFu;
    for (int s = 0; s < S; ++s) {
        int i = s * 64 + lane;
        unsigned vb = (i < (int)C) ? sv_val[w][i] : 0xFFFFFFFFu;
        unsigned mi = (i < (int)C) ? sv_idx[w][i] : 0xFFFFFFFFu;
        if (vb == Vmin && mi < imin_l) imin_l = mi;
    }
#pragma unroll
    for (int off = 32; off >= 1; off >>= 1) {
        unsigned o2 = __shfl_xor(imin_l, off, 64);
        imin_l = imin_l < o2 ? imin_l : o2;
    }
    const unsigned dropIdx = imin_l;

    int* o = idx_out + (size_t)gq * KNN;
    unsigned wbase = 0, tbase = 0;
    for (int s = 0; s < S; ++s) {
        int i = s * 64 + lane;
        unsigned vb = (i < (int)C) ? sv_val[w][i] : 0xFFFFFFFFu;
        unsigned mi = (i < (int)C) ? sv_idx[w][i] : 0xFFFFFFFFu;
        bool wk = (vb < Ts) && (mi != dropIdx);
        unsigned long long wm = __ballot(wk);
        if (wk) o[wbase + (unsigned)__popcll(wm & lt)] = (int)mi;
        wbase += (unsigned)__popcll(wm);
        bool tk = (vb == Ts);
        unsigned long long tm2 = __ballot(tk);
        if (tk) {
            unsigned tp = tbase + (unsigned)__popcll(tm2 & lt);
            if (tp < 64) tie_idx[w][tp] = mi;
        }
        tbase += (unsigned)__popcll(tm2);
    }
    unsigned tc = tbase > 64 ? 64 : tbase;
    if ((int)tc == need) {
        bool tk = (lane < (int)tc);
        unsigned mi2 = tk ? tie_idx[w][lane] : 0xFFFFFFFFu;
        tk = tk && (mi2 != dropIdx);
        unsigned long long m3 = __ballot(tk);
        if (tk) o[wbase + (unsigned)__popcll(m3 & lt)] = (int)mi2;
    } else if (lane == 0) {
        unsigned pos = wbase;
        for (int r = 0; r < need; ++r) {
            unsigned best = 0xFFFFFFFFu; int bj = 0;
            for (int j2 = 0; j2 < (int)tc; ++j2) {
                unsigned mi = tie_idx[w][j2];
                if (mi < best) { best = mi; bj = j2; }
            }
            tie_idx[w][bj] = 0xFFFFFFFFu;
            if (best != dropIdx) o[pos++] = (int)best;
        }
    }
}

// ---------------- gq_gemm: G = feat@W1a (bf16), Q = feat@Wd + b1 (bf16) -------------
__global__ __launch_bounds__(256, 4) void gq_gemm(const float* __restrict__ feat,
                                                  const __bf16* __restrict__ Wcf,
                                                  const float* __restrict__ b1,
                                                  __bf16* __restrict__ Gall,
                                                  __bf16* __restrict__ Qall) {
    __shared__ __align__(16) __bf16 st[4][16][136];
    const int t = threadIdx.x, w = t >> 6, lane = t & 63;
    const int quad = lane >> 4, l16 = lane & 15;
    const int m0 = blockIdx.x * 16;

    bf16x8 a[2];
#pragma unroll
    for (int kk = 0; kk < 2; ++kk) {
        const float* ap = feat + (size_t)(m0 + l16) * 64 + kk * 32 + quad * 8;
        float4 a0 = *(const float4*)ap, a1 = *(const float4*)(ap + 4);
        bf16x8 v;
        v[0] = (__bf16)a0.x; v[1] = (__bf16)a0.y; v[2] = (__bf16)a0.z; v[3] = (__bf16)a0.w;
        v[4] = (__bf16)a1.x; v[5] = (__bf16)a1.y; v[6] = (__bf16)a1.z; v[7] = (__bf16)a1.w;
        a[kk] = v;
    }
    f32x4 acc[8];
#pragma unroll
    for (int nt = 0; nt < 8; ++nt) acc[nt] = (f32x4){0.f, 0.f, 0.f, 0.f};
#pragma unroll
    for (int kk = 0; kk < 2; ++kk)
#pragma unroll
        for (int nt = 0; nt < 8; ++nt) {
            bf16x8 bf = *(const bf16x8*)(Wcf + (size_t)(((w * 8 + nt) * 2 + kk) * 64 + lane) * 8);
            acc[nt] = __builtin_amdgcn_mfma_f32_16x16x32_bf16(a[kk], bf, acc[nt], 0, 0, 0);
        }

    const bool isQ = (w >= 2);
#pragma unroll
    for (int nt = 0; nt < 8; ++nt) {
        const int col = nt * 16 + l16;
        const float bias = isQ ? b1[(w - 2) * 128 + col] : 0.f;
#pragma unroll
        for (int r = 0; r < 4; ++r)
            st[w][quad * 4 + r][col] = (__bf16)(acc[nt][r] + bias);
    }
    __syncthreads();

    const int row = lane >> 2, c = lane & 3;
    const int m = m0 + row;
#pragma unroll
    for (int i = 0; i < 4; ++i) {
        const int col = c * 32 + i * 8;
        bf16x8 v = *(const bf16x8*)&st[w][row][col];
        if (!isQ) *(bf16x8*)(Gall + (size_t)m * H2 + w * 128 + col) = v;
        else      *(bf16x8*)(Qall + (size_t)m * H2 + (w - 2) * 128 + col) = v;
    }
}

// ---------------- fused_mlp6: out = mean_k gelu(gelu(G[idx]+Q) @ W2 + b2) -----------
// mlp3 per-wave shape (2 queries/wave, LDS B-frags) but W2f staged in two 32 KB
// halves -> 4 blocks/CU = 32 waves/CU (2x mlp3 residency). 2048 blocks x 8 waves.
__global__ __launch_bounds__(512, 8) void fused_mlp6(const __bf16* __restrict__ Gall,
                                                     const __bf16* __restrict__ Qall,
                                                     const int* __restrict__ knn_idx,
                                                     const __bf16* __restrict__ W2f,
                                                     const float* __restrict__ b2,
                                                     float* __restrict__ out) {
    __shared__ __align__(16) __bf16 w2s[16384];   // 32 KB: one kk8-half of W2f
    const int t = threadIdx.x, w = t >> 6, lane = t & 63;
    const int quad = lane >> 4, l16 = lane & 15;

    const int wave_id = blockIdx.x * 8 + w;       // [0, 16384)
    const int q0 = wave_id * 2;                   // queries q0, q0+1
    const int b = q0 >> 10;
    const int nb0 = knn_idx[q0 * KNN + l16];
    const int nb1 = knn_idx[(q0 + 1) * KNN + l16];
    const __bf16* g0 = Gall + ((size_t)(b << 10) + nb0) * H2;
    const __bf16* g1 = Gall + ((size_t)(b << 10) + nb1) * H2;
    const __bf16* qq0 = Qall + (size_t)q0 * H2;
    const __bf16* qq1 = qq0 + H2;

    f32x4 acc[2][8];
#pragma unroll
    for (int tm = 0; tm < 2; ++tm)
#pragma unroll
        for (int nt = 0; nt < 8; ++nt) acc[tm][nt] = (f32x4){0.f, 0.f, 0.f, 0.f};

#pragma unroll
    for (int half = 0; half < 2; ++half) {
        if (half) __syncthreads();   // all waves done reading previous half
#pragma unroll
        for (int i = 0; i < 4; ++i) {
            bf16x8 v = *(const bf16x8*)(W2f + (size_t)(half * 2048 + i * 512 + t) * 8);
            *(bf16x8*)&w2s[(size_t)(i * 512 + t) * 8] = v;
        }
        __syncthreads();

#pragma unroll
        for (int kl = 0; kl < 4; ++kl) {
            const int ho = (half * 4 + kl) * 32 + quad * 8;
            bf16x8 gA = *(const bf16x8*)(g0 + ho);
            bf16x8 qA = *(const bf16x8*)(qq0 + ho);
            bf16x8 gB = *(const bf16x8*)(g1 + ho);
            bf16x8 qB = *(const bf16x8*)(qq1 + ho);
            bf16x8 a0, a1;
#pragma unroll
            for (int j = 0; j < 8; ++j) {
                a0[j] = (__bf16)gelu_fast((float)gA[j] + (float)qA[j]);
                a1[j] = (__bf16)gelu_fast((float)gB[j] + (float)qB[j]);
            }
            const __bf16* bb = &w2s[(kl * 8) * 512 + lane * 8];
#pragma unroll
            for (int nt = 0; nt < 8; ++nt) {
                bf16x8 bf = *(const bf16x8*)(bb + nt * 512);
                acc[0][nt] = __builtin_amdgcn_mfma_f32_16x16x32_bf16(a0, bf, acc[0][nt], 0, 0, 0);
                acc[1][nt] = __builtin_amdgcn_mfma_f32_16x16x32_bf16(a1, bf, acc[1][nt], 0, 0, 0);
            }
        }
    }

#pragma unroll
    for (int tm = 0; tm < 2; ++tm)
#pragma unroll
        for (int nt = 0; nt < 8; ++nt) {
            const float bias = b2[nt * 16 + l16];
            float s = 0.f;
#pragma unroll
            for (int r = 0; r < 4; ++r) s += gelu_fast(acc[tm][nt][r] + bias);
            s += __shfl_xor(s, 16, 64);
            s += __shfl_xor(s, 32, 64);
            if (quad == 0)
                out[(size_t)(q0 + tm) * PP + nt * 16 + l16] = s * 0.0625f;
        }
}

extern "C" void kernel_launch(void* const* d_in, const int* in_sizes, int n_in,
                              void* d_out, int out_size, void* d_ws, size_t ws_size,
                              hipStream_t stream) {
    const float* points   = (const float*)d_in[0];
    const float* features = (const float*)d_in[1];
    const float* W1 = (const float*)d_in[2];
    const float* b1 = (const float*)d_in[3];
    const float* W2 = (const float*)d_in[4];
    const float* b2 = (const float*)d_in[5];
    float* out = (float*)d_out;

    const size_t IDX_B  = (size_t)BB * NN * KNN * 4;   // 2 MB
    const size_t WCF_B  = 512 * 64 * 2;                // 64 KB
    const size_t W2F_B  = 256 * 128 * 2;               // 64 KB
    const size_t G_B    = (size_t)BB * NN * H2 * 2;    // 16 MB

    int* knn_idx = (int*)d_ws;
    char* p = (char*)d_ws + IDX_B;
    __bf16* Wcf  = (__bf16*)p;  p += WCF_B;
    __bf16* W2f  = (__bf16*)p;  p += W2F_B;
    __bf16* Gall = (__bf16*)p;  p += G_B;
    __bf16* Qall = (__bf16*)p;                         // 16 MB -> total ~34.1 MB

    knn_prep<<<4112, 512, 0, stream>>>(points, knn_idx, W1, W2, Wcf, W2f);
    gq_gemm<<<2048, 256, 0, stream>>>(features, Wcf, b1, Gall, Qall);
    fused_mlp6<<<2048, 512, 0, stream>>>(Gall, Qall, knn_idx, W2f, b2, out);
}

// Round 9
// 213.839 us; speedup vs baseline: 2.2351x; 2.2351x over previous
//
#include <hip/hip_runtime.h>
#include <math.h>

#define BB 32
#define NN 1024
#define FF 64
#define PP 128
#define KNN 16
#define H2 256  // 2P
#define F2 128  // 2F
#define KSEL 17
#define SVCAP 272

typedef float f32x4 __attribute__((ext_vector_type(4)));
typedef __bf16 bf16x8 __attribute__((ext_vector_type(8)));

__device__ __forceinline__ float gelu_fast(float x) {
    // x * sigmoid(2.3022115x + 0.1029438x^3); |err vs exact gelu| ~3e-4
    float s = x * x;
    float arg = x * fmaf(s, -0.1029438f, -2.3022115f);
    float e = __builtin_amdgcn_exp2f(arg);
    return x * __builtin_amdgcn_rcpf(1.0f + e);
}

// ------- Kernel A: set-based kNN (blocks 0..4095) + weight-frag prep (4096..4111) ---
__global__ __launch_bounds__(512, 8) void knn_prep(const float* __restrict__ points,
                                                   int* __restrict__ idx_out,
                                                   const float* __restrict__ W1,
                                                   const float* __restrict__ W2,
                                                   __bf16* __restrict__ Wcf,
                                                   __bf16* __restrict__ W2f) {
    if (blockIdx.x >= 4096) {
        // ---- prep path: fragment-swizzled Wcf (gq_gemm B) + W2f (fused B) ----
        int tid = (blockIdx.x - 4096) * 512 + threadIdx.x;   // 0..8191
        if (tid < 4096) {
            const int lane = tid & 63, quad = lane >> 4, l16 = lane & 15;
            const int kk = (tid >> 6) & 1, n_tile = tid >> 7;
            const int n = n_tile * 16 + l16;
            const int kb = kk * 32 + quad * 8;
            bf16x8 v;
#pragma unroll
            for (int j = 0; j < 8; ++j) {
                const int k = kb + j;
                float x = (n < 256) ? W1[k * 256 + n]
                                    : (W1[(64 + k) * 256 + (n - 256)] - W1[k * 256 + (n - 256)]);
                v[j] = (__bf16)x;
            }
            *(bf16x8*)(Wcf + (size_t)tid * 8) = v;
        } else {
            const int t2 = tid - 4096;
            const int lane = t2 & 63, quad = lane >> 4, l16 = lane & 15;
            const int nt = (t2 >> 6) & 7, kk8 = t2 >> 9;
            const int p = nt * 16 + l16;
            const int hb = kk8 * 32 + quad * 8;
            bf16x8 v;
#pragma unroll
            for (int j = 0; j < 8; ++j) v[j] = (__bf16)W2[(size_t)(hb + j) * PP + p];
            *(bf16x8*)(W2f + (size_t)t2 * 8) = v;
        }
        return;
    }

    __shared__ float4 pts[NN];
    __shared__ unsigned sv_val[8][SVCAP];
    __shared__ unsigned sv_idx[8][SVCAP];
    __shared__ unsigned tie_idx[8][64];

    const int t = threadIdx.x;
    const int w = t >> 6, lane = t & 63;
    const int b = blockIdx.x >> 7;
    const int q0 = (blockIdx.x & 127) * 8;
    const float* pb = points + (size_t)b * NN * 3;
    const unsigned long long lt = (1ull << lane) - 1ull;

    for (int i = t; i < NN; i += 512) {
        float x = pb[3 * i], y = pb[3 * i + 1], z = pb[3 * i + 2];
        float r = __fadd_rn(__fadd_rn(__fmul_rn(x, x), __fmul_rn(y, y)), __fmul_rn(z, z));
        pts[i] = make_float4(x, y, z, r);
    }
    __syncthreads();

    const int qn = q0 + w;
    const int gq = b * NN + qn;
    const float4 qp = pts[qn];

    float D[16];
#pragma unroll
    for (int j = 0; j < 16; ++j) {
        float4 c = pts[j * 64 + lane];
        float dot = __fadd_rn(__fadd_rn(__fmul_rn(qp.x, c.x), __fmul_rn(qp.y, c.y)),
                              __fmul_rn(qp.z, c.z));
        D[j] = __fadd_rn(__fadd_rn(__fsub_rn(qp.w, __fmul_rn(2.0f, dot)), c.w), 1e-5f);
    }

    float mnf = D[0];
#pragma unroll
    for (int j = 1; j < 16; ++j) mnf = fminf(mnf, D[j]);
    const unsigned mbits = __float_as_uint(mnf);

    unsigned T = 0;
#pragma unroll
    for (int bit = 31; bit >= 0; --bit) {
        unsigned cand = T | (1u << bit);
        int cnt = __popcll(__ballot(mbits < cand));
        if (cnt < KSEL) T = cand;
    }

    unsigned base = 0;
#pragma unroll
    for (int j = 0; j < 16; ++j) {
        unsigned vb = __float_as_uint(D[j]);
        bool keep = (vb <= T);
        unsigned long long m = __ballot(keep);
        if (keep) {
            unsigned pos = base + (unsigned)__popcll(m & lt);
            if (pos < SVCAP) { sv_val[w][pos] = vb; sv_idx[w][pos] = j * 64 + lane; }
        }
        base += (unsigned)__popcll(m);
    }
    unsigned C = base > SVCAP ? SVCAP : base;
    const int S = (int)((C + 63) >> 6);

    unsigned Ts = 0;
    if (S == 1) {
        unsigned xv0 = (lane < (int)C) ? sv_val[w][lane] : 0xFFFFFFFFu;
#pragma unroll
        for (int bit = 31; bit >= 0; --bit) {
            unsigned cand = Ts | (1u << bit);
            int cnt = __popcll(__ballot(xv0 < cand));
            if (cnt < KSEL) Ts = cand;
        }
    } else {
        for (int bit = 31; bit >= 0; --bit) {
            unsigned cand = Ts | (1u << bit);
            int cnt = 0;
            for (int s = 0; s < S; ++s) {
                int i = s * 64 + lane;
                unsigned vb = (i < (int)C) ? sv_val[w][i] : 0xFFFFFFFFu;
                cnt += __popcll(__ballot(vb < cand));
            }
            if (cnt < KSEL) Ts = cand;
        }
    }

    int L = 0;
    for (int s = 0; s < S; ++s) {
        int i = s * 64 + lane;
        unsigned vb = (i < (int)C) ? sv_val[w][i] : 0xFFFFFFFFu;
        L += __popcll(__ballot(vb < Ts));
    }
    const int need = KSEL - L;

    unsigned vmin_l = 0xFFFFFFFFu;
    for (int s = 0; s < S; ++s) {
        int i = s * 64 + lane;
        unsigned vb = (i < (int)C) ? sv_val[w][i] : 0xFFFFFFFFu;
        vmin_l = vmin_l < vb ? vmin_l : vb;
    }
#pragma unroll
    for (int off = 32; off >= 1; off >>= 1) {
        unsigned o2 = __shfl_xor(vmin_l, off, 64);
        vmin_l = vmin_l < o2 ? vmin_l : o2;
    }
    const unsigned Vmin = vmin_l;
    unsigned imin_l = 0xFFFFFFFFu;
    for (int s = 0; s < S; ++s) {
        int i = s * 64 + lane;
        unsigned vb = (i < (int)C) ? sv_val[w][i] : 0xFFFFFFFFu;
        unsigned mi = (i < (int)C) ? sv_idx[w][i] : 0xFFFFFFFFu;
        if (vb == Vmin && mi < imin_l) imin_l = mi;
    }
#pragma unroll
    for (int off = 32; off >= 1; off >>= 1) {
        unsigned o2 = __shfl_xor(imin_l, off, 64);
        imin_l = imin_l < o2 ? imin_l : o2;
    }
    const unsigned dropIdx = imin_l;

    int* o = idx_out + (size_t)gq * KNN;
    unsigned wbase = 0, tbase = 0;
    for (int s = 0; s < S; ++s) {
        int i = s * 64 + lane;
        unsigned vb = (i < (int)C) ? sv_val[w][i] : 0xFFFFFFFFu;
        unsigned mi = (i < (int)C) ? sv_idx[w][i] : 0xFFFFFFFFu;
        bool wk = (vb < Ts) && (mi != dropIdx);
        unsigned long long wm = __ballot(wk);
        if (wk) o[wbase + (unsigned)__popcll(wm & lt)] = (int)mi;
        wbase += (unsigned)__popcll(wm);
        bool tk = (vb == Ts);
        unsigned long long tm2 = __ballot(tk);
        if (tk) {
            unsigned tp = tbase + (unsigned)__popcll(tm2 & lt);
            if (tp < 64) tie_idx[w][tp] = mi;
        }
        tbase += (unsigned)__popcll(tm2);
    }
    unsigned tc = tbase > 64 ? 64 : tbase;
    if ((int)tc == need) {
        bool tk = (lane < (int)tc);
        unsigned mi2 = tk ? tie_idx[w][lane] : 0xFFFFFFFFu;
        tk = tk && (mi2 != dropIdx);
        unsigned long long m3 = __ballot(tk);
        if (tk) o[wbase + (unsigned)__popcll(m3 & lt)] = (int)mi2;
    } else if (lane == 0) {
        unsigned pos = wbase;
        for (int r = 0; r < need; ++r) {
            unsigned best = 0xFFFFFFFFu; int bj = 0;
            for (int j2 = 0; j2 < (int)tc; ++j2) {
                unsigned mi = tie_idx[w][j2];
                if (mi < best) { best = mi; bj = j2; }
            }
            tie_idx[w][bj] = 0xFFFFFFFFu;
            if (best != dropIdx) o[pos++] = (int)best;
        }
    }
}

// ---------------- gq_gemm: G = feat@W1a (bf16), Q = feat@Wd + b1 (bf16) -------------
__global__ __launch_bounds__(256, 4) void gq_gemm(const float* __restrict__ feat,
                                                  const __bf16* __restrict__ Wcf,
                                                  const float* __restrict__ b1,
                                                  __bf16* __restrict__ Gall,
                                                  __bf16* __restrict__ Qall) {
    __shared__ __align__(16) __bf16 st[4][16][136];
    const int t = threadIdx.x, w = t >> 6, lane = t & 63;
    const int quad = lane >> 4, l16 = lane & 15;
    const int m0 = blockIdx.x * 16;

    bf16x8 a[2];
#pragma unroll
    for (int kk = 0; kk < 2; ++kk) {
        const float* ap = feat + (size_t)(m0 + l16) * 64 + kk * 32 + quad * 8;
        float4 a0 = *(const float4*)ap, a1 = *(const float4*)(ap + 4);
        bf16x8 v;
        v[0] = (__bf16)a0.x; v[1] = (__bf16)a0.y; v[2] = (__bf16)a0.z; v[3] = (__bf16)a0.w;
        v[4] = (__bf16)a1.x; v[5] = (__bf16)a1.y; v[6] = (__bf16)a1.z; v[7] = (__bf16)a1.w;
        a[kk] = v;
    }
    f32x4 acc[8];
#pragma unroll
    for (int nt = 0; nt < 8; ++nt) acc[nt] = (f32x4){0.f, 0.f, 0.f, 0.f};
#pragma unroll
    for (int kk = 0; kk < 2; ++kk)
#pragma unroll
        for (int nt = 0; nt < 8; ++nt) {
            bf16x8 bf = *(const bf16x8*)(Wcf + (size_t)(((w * 8 + nt) * 2 + kk) * 64 + lane) * 8);
            acc[nt] = __builtin_amdgcn_mfma_f32_16x16x32_bf16(a[kk], bf, acc[nt], 0, 0, 0);
        }

    const bool isQ = (w >= 2);
#pragma unroll
    for (int nt = 0; nt < 8; ++nt) {
        const int col = nt * 16 + l16;
        const float bias = isQ ? b1[(w - 2) * 128 + col] : 0.f;
#pragma unroll
        for (int r = 0; r < 4; ++r)
            st[w][quad * 4 + r][col] = (__bf16)(acc[nt][r] + bias);
    }
    __syncthreads();

    const int row = lane >> 2, c = lane & 3;
    const int m = m0 + row;
#pragma unroll
    for (int i = 0; i < 4; ++i) {
        const int col = c * 32 + i * 8;
        bf16x8 v = *(const bf16x8*)&st[w][row][col];
        if (!isQ) *(bf16x8*)(Gall + (size_t)m * H2 + w * 128 + col) = v;
        else      *(bf16x8*)(Qall + (size_t)m * H2 + (w - 2) * 128 + col) = v;
    }
}

// ---------------- fused_mlp6: out = mean_k gelu(gelu(G[idx]+Q) @ W2 + b2) -----------
// mlp3 per-wave shape (2 queries/wave, LDS B-frags) but W2f staged in two 32 KB
// halves. __launch_bounds__(512,4): VGPR cap 128 (compiler uses ~64, NO SPILL);
// hardware occupancy = min(VGPR 8 waves/SIMD, LDS 5 blocks/CU, cap) = 4 blocks/CU.
__global__ __launch_bounds__(512, 4) void fused_mlp6(const __bf16* __restrict__ Gall,
                                                     const __bf16* __restrict__ Qall,
                                                     const int* __restrict__ knn_idx,
                                                     const __bf16* __restrict__ W2f,
                                                     const float* __restrict__ b2,
                                                     float* __restrict__ out) {
    __shared__ __align__(16) __bf16 w2s[16384];   // 32 KB: one kk8-half of W2f
    const int t = threadIdx.x, w = t >> 6, lane = t & 63;
    const int quad = lane >> 4, l16 = lane & 15;

    const int wave_id = blockIdx.x * 8 + w;       // [0, 16384)
    const int q0 = wave_id * 2;                   // queries q0, q0+1
    const int b = q0 >> 10;
    const int nb0 = knn_idx[q0 * KNN + l16];
    const int nb1 = knn_idx[(q0 + 1) * KNN + l16];
    const __bf16* g0 = Gall + ((size_t)(b << 10) + nb0) * H2;
    const __bf16* g1 = Gall + ((size_t)(b << 10) + nb1) * H2;
    const __bf16* qq0 = Qall + (size_t)q0 * H2;
    const __bf16* qq1 = qq0 + H2;

    f32x4 acc[2][8];
#pragma unroll
    for (int tm = 0; tm < 2; ++tm)
#pragma unroll
        for (int nt = 0; nt < 8; ++nt) acc[tm][nt] = (f32x4){0.f, 0.f, 0.f, 0.f};

#pragma unroll
    for (int half = 0; half < 2; ++half) {
        if (half) __syncthreads();   // all waves done reading previous half
#pragma unroll
        for (int i = 0; i < 4; ++i) {
            bf16x8 v = *(const bf16x8*)(W2f + (size_t)(half * 2048 + i * 512 + t) * 8);
            *(bf16x8*)&w2s[(size_t)(i * 512 + t) * 8] = v;
        }
        __syncthreads();

#pragma unroll
        for (int kl = 0; kl < 4; ++kl) {
            const int ho = (half * 4 + kl) * 32 + quad * 8;
            bf16x8 gA = *(const bf16x8*)(g0 + ho);
            bf16x8 qA = *(const bf16x8*)(qq0 + ho);
            bf16x8 gB = *(const bf16x8*)(g1 + ho);
            bf16x8 qB = *(const bf16x8*)(qq1 + ho);
            bf16x8 a0, a1;
#pragma unroll
            for (int j = 0; j < 8; ++j) {
                a0[j] = (__bf16)gelu_fast((float)gA[j] + (float)qA[j]);
                a1[j] = (__bf16)gelu_fast((float)gB[j] + (float)qB[j]);
            }
            const __bf16* bb = &w2s[(kl * 8) * 512 + lane * 8];
#pragma unroll
            for (int nt = 0; nt < 8; ++nt) {
                bf16x8 bf = *(const bf16x8*)(bb + nt * 512);
                acc[0][nt] = __builtin_amdgcn_mfma_f32_16x16x32_bf16(a0, bf, acc[0][nt], 0, 0, 0);
                acc[1][nt] = __builtin_amdgcn_mfma_f32_16x16x32_bf16(a1, bf, acc[1][nt], 0, 0, 0);
            }
        }
    }

#pragma unroll
    for (int tm = 0; tm < 2; ++tm)
#pragma unroll
        for (int nt = 0; nt < 8; ++nt) {
            const float bias = b2[nt * 16 + l16];
            float s = 0.f;
#pragma unroll
            for (int r = 0; r < 4; ++r) s += gelu_fast(acc[tm][nt][r] + bias);
            s += __shfl_xor(s, 16, 64);
            s += __shfl_xor(s, 32, 64);
            if (quad == 0)
                out[(size_t)(q0 + tm) * PP + nt * 16 + l16] = s * 0.0625f;
        }
}

extern "C" void kernel_launch(void* const* d_in, const int* in_sizes, int n_in,
                              void* d_out, int out_size, void* d_ws, size_t ws_size,
                              hipStream_t stream) {
    const float* points   = (const float*)d_in[0];
    const float* features = (const float*)d_in[1];
    const float* W1 = (const float*)d_in[2];
    const float* b1 = (const float*)d_in[3];
    const float* W2 = (const float*)d_in[4];
    const float* b2 = (const float*)d_in[5];
    float* out = (float*)d_out;

    const size_t IDX_B  = (size_t)BB * NN * KNN * 4;   // 2 MB
    const size_t WCF_B  = 512 * 64 * 2;                // 64 KB
    const size_t W2F_B  = 256 * 128 * 2;               // 64 KB
    const size_t G_B    = (size_t)BB * NN * H2 * 2;    // 16 MB

    int* knn_idx = (int*)d_ws;
    char* p = (char*)d_ws + IDX_B;
    __bf16* Wcf  = (__bf16*)p;  p += WCF_B;
    __bf16* W2f  = (__bf16*)p;  p += W2F_B;
    __bf16* Gall = (__bf16*)p;  p += G_B;
    __bf16* Qall = (__bf16*)p;                         // 16 MB -> total ~34.1 MB

    knn_prep<<<4112, 512, 0, stream>>>(points, knn_idx, W1, W2, Wcf, W2f);
    gq_gemm<<<2048, 256, 0, stream>>>(features, Wcf, b1, Gall, Qall);
    fused_mlp6<<<2048, 512, 0, stream>>>(Gall, Qall, knn_idx, W2f, b2, out);
}

// Round 10
// 205.876 us; speedup vs baseline: 2.3216x; 1.0387x over previous
//
#include <hip/hip_runtime.h>
#include <math.h>

#define BB 32
#define NN 1024
#define FF 64
#define PP 128
#define KNN 16
#define H2 256  // 2P
#define F2 128  // 2F
#define KSEL 17
#define SVCAP 272

typedef float f32x4 __attribute__((ext_vector_type(4)));
typedef __bf16 bf16x8 __attribute__((ext_vector_type(8)));

__device__ __forceinline__ float gelu_fast(float x) {
    // x * sigmoid(2.3022115x + 0.1029438x^3); |err vs exact gelu| ~3e-4
    float s = x * x;
    float arg = x * fmaf(s, -0.1029438f, -2.3022115f);
    float e = __builtin_amdgcn_exp2f(arg);
    return x * __builtin_amdgcn_rcpf(1.0f + e);
}

// ------- Kernel A: set-based kNN (blocks 0..4095) + weight-frag prep (4096..4111) ---
__global__ __launch_bounds__(512, 8) void knn_prep(const float* __restrict__ points,
                                                   int* __restrict__ idx_out,
                                                   const float* __restrict__ W1,
                                                   const float* __restrict__ W2,
                                                   __bf16* __restrict__ Wcf,
                                                   __bf16* __restrict__ W2f) {
    if (blockIdx.x >= 4096) {
        // ---- prep path: fragment-swizzled Wcf (gq_gemm B) + W2f (fused B) ----
        int tid = (blockIdx.x - 4096) * 512 + threadIdx.x;   // 0..8191
        if (tid < 4096) {
            const int lane = tid & 63, quad = lane >> 4, l16 = lane & 15;
            const int kk = (tid >> 6) & 1, n_tile = tid >> 7;
            const int n = n_tile * 16 + l16;
            const int kb = kk * 32 + quad * 8;
            bf16x8 v;
#pragma unroll
            for (int j = 0; j < 8; ++j) {
                const int k = kb + j;
                float x = (n < 256) ? W1[k * 256 + n]
                                    : (W1[(64 + k) * 256 + (n - 256)] - W1[k * 256 + (n - 256)]);
                v[j] = (__bf16)x;
            }
            *(bf16x8*)(Wcf + (size_t)tid * 8) = v;
        } else {
            const int t2 = tid - 4096;
            const int lane = t2 & 63, quad = lane >> 4, l16 = lane & 15;
            const int nt = (t2 >> 6) & 7, kk8 = t2 >> 9;
            const int p = nt * 16 + l16;
            const int hb = kk8 * 32 + quad * 8;
            bf16x8 v;
#pragma unroll
            for (int j = 0; j < 8; ++j) v[j] = (__bf16)W2[(size_t)(hb + j) * PP + p];
            *(bf16x8*)(W2f + (size_t)t2 * 8) = v;
        }
        return;
    }

    // SoA point storage: stride-4B LDS reads are bank-conflict-free (float4 layout
    // had stride-16B => 8-way conflict on every hot-loop read).
    __shared__ float px[NN], py[NN], pz[NN], rr[NN];
    __shared__ unsigned sv_val[8][SVCAP];
    __shared__ unsigned sv_idx[8][SVCAP];
    __shared__ unsigned tie_idx[8][64];

    const int t = threadIdx.x;
    const int w = t >> 6, lane = t & 63;
    const int b = blockIdx.x >> 7;
    const int q0 = (blockIdx.x & 127) * 8;
    const float* pb = points + (size_t)b * NN * 3;
    const unsigned long long lt = (1ull << lane) - 1ull;

    for (int i = t; i < NN; i += 512) {
        float x = pb[3 * i], y = pb[3 * i + 1], z = pb[3 * i + 2];
        px[i] = x; py[i] = y; pz[i] = z;
        rr[i] = __fadd_rn(__fadd_rn(__fmul_rn(x, x), __fmul_rn(y, y)), __fmul_rn(z, z));
    }
    __syncthreads();

    const int qn = q0 + w;
    const int gq = b * NN + qn;
    const float qx = px[qn], qy = py[qn], qz = pz[qn], qw = rr[qn];

    float D[16];
#pragma unroll
    for (int j = 0; j < 16; ++j) {
        const int m = j * 64 + lane;
        float dot = __fadd_rn(__fadd_rn(__fmul_rn(qx, px[m]), __fmul_rn(qy, py[m])),
                              __fmul_rn(qz, pz[m]));
        D[j] = __fadd_rn(__fadd_rn(__fsub_rn(qw, __fmul_rn(2.0f, dot)), rr[m]), 1e-5f);
    }

    float mnf = D[0];
#pragma unroll
    for (int j = 1; j < 16; ++j) mnf = fminf(mnf, D[j]);
    const unsigned mbits = __float_as_uint(mnf);

    // T_ub via 16-round radix on the HIGH 16 bits of the lane-mins.
    // Invariant: Thi = max prefix with #{hi < Thi} < 17  =>  #{hi <= Thi} >= 17
    // => >=17 distinct values (one per lane) <= T := (Thi<<16)|0xFFFF => v17 <= T.
    const unsigned mhi = mbits >> 16;
    unsigned Thi = 0;
#pragma unroll
    for (int bit = 15; bit >= 0; --bit) {
        unsigned cand = Thi | (1u << bit);
        int cnt = __popcll(__ballot(mhi < cand));
        if (cnt < KSEL) Thi = cand;
    }
    const unsigned T = (Thi << 16) | 0xFFFFu;

    unsigned base = 0;
#pragma unroll
    for (int j = 0; j < 16; ++j) {
        unsigned vb = __float_as_uint(D[j]);
        bool keep = (vb <= T);
        unsigned long long m = __ballot(keep);
        if (keep) {
            unsigned pos = base + (unsigned)__popcll(m & lt);
            if (pos < SVCAP) { sv_val[w][pos] = vb; sv_idx[w][pos] = j * 64 + lane; }
        }
        base += (unsigned)__popcll(m);
    }
    unsigned C = base > SVCAP ? SVCAP : base;
    const int S = (int)((C + 63) >> 6);

    unsigned Ts = 0;
    if (S == 1) {
        unsigned xv0 = (lane < (int)C) ? sv_val[w][lane] : 0xFFFFFFFFu;
#pragma unroll
        for (int bit = 31; bit >= 0; --bit) {
            unsigned cand = Ts | (1u << bit);
            int cnt = __popcll(__ballot(xv0 < cand));
            if (cnt < KSEL) Ts = cand;
        }
    } else {
        for (int bit = 31; bit >= 0; --bit) {
            unsigned cand = Ts | (1u << bit);
            int cnt = 0;
            for (int s = 0; s < S; ++s) {
                int i = s * 64 + lane;
                unsigned vb = (i < (int)C) ? sv_val[w][i] : 0xFFFFFFFFu;
                cnt += __popcll(__ballot(vb < cand));
            }
            if (cnt < KSEL) Ts = cand;
        }
    }

    int L = 0;
    for (int s = 0; s < S; ++s) {
        int i = s * 64 + lane;
        unsigned vb = (i < (int)C) ? sv_val[w][i] : 0xFFFFFFFFu;
        L += __popcll(__ballot(vb < Ts));
    }
    const int need = KSEL - L;

    unsigned vmin_l = 0xFFFFFFFFu;
    for (int s = 0; s < S; ++s) {
        int i = s * 64 + lane;
        unsigned vb = (i < (int)C) ? sv_val[w][i] : 0xFFFFFFFFu;
        vmin_l = vmin_l < vb ? vmin_l : vb;
    }
#pragma unroll
    for (int off = 32; off >= 1; off >>= 1) {
        unsigned o2 = __shfl_xor(vmin_l, off, 64);
        vmin_l = vmin_l < o2 ? vmin_l : o2;
    }
    const unsigned Vmin = vmin_l;
    unsigned imin_l = 0xFFFFFFFFu;
    for (int s = 0; s < S; ++s) {
        int i = s * 64 + lane;
        unsigned vb = (i < (int)C) ? sv_val[w][i] : 0xFFFFFFFFu;
        unsigned mi = (i < (int)C) ? sv_idx[w][i] : 0xFFFFFFFFu;
        if (vb == Vmin && mi < imin_l) imin_l = mi;
    }
#pragma unroll
    for (int off = 32; off >= 1; off >>= 1) {
        unsigned o2 = __shfl_xor(imin_l, off, 64);
        imin_l = imin_l < o2 ? imin_l : o2;
    }
    const unsigned dropIdx = imin_l;

    int* o = idx_out + (size_t)gq * KNN;
    unsigned wbase = 0, tbase = 0;
    for (int s = 0; s < S; ++s) {
        int i = s * 64 + lane;
        unsigned vb = (i < (int)C) ? sv_val[w][i] : 0xFFFFFFFFu;
        unsigned mi = (i < (int)C) ? sv_idx[w][i] : 0xFFFFFFFFu;
        bool wk = (vb < Ts) && (mi != dropIdx);
        unsigned long long wm = __ballot(wk);
        if (wk) o[wbase + (unsigned)__popcll(wm & lt)] = (int)mi;
        wbase += (unsigned)__popcll(wm);
        bool tk = (vb == Ts);
        unsigned long long tm2 = __ballot(tk);
        if (tk) {
            unsigned tp = tbase + (unsigned)__popcll(tm2 & lt);
            if (tp < 64) tie_idx[w][tp] = mi;
        }
        tbase += (unsigned)__popcll(tm2);
    }
    unsigned tc = tbase > 64 ? 64 : tbase;
    if ((int)tc == need) {
        bool tk = (lane < (int)tc);
        unsigned mi2 = tk ? tie_idx[w][lane] : 0xFFFFFFFFu;
        tk = tk && (mi2 != dropIdx);
        unsigned long long m3 = __ballot(tk);
        if (tk) o[wbase + (unsigned)__popcll(m3 & lt)] = (int)mi2;
    } else if (lane == 0) {
        unsigned pos = wbase;
        for (int r = 0; r < need; ++r) {
            unsigned best = 0xFFFFFFFFu; int bj = 0;
            for (int j2 = 0; j2 < (int)tc; ++j2) {
                unsigned mi = tie_idx[w][j2];
                if (mi < best) { best = mi; bj = j2; }
            }
            tie_idx[w][bj] = 0xFFFFFFFFu;
            if (best != dropIdx) o[pos++] = (int)best;
        }
    }
}

// ---------------- gq_gemm: G = feat@W1a (bf16), Q = feat@Wd + b1 (bf16) -------------
__global__ __launch_bounds__(256, 4) void gq_gemm(const float* __restrict__ feat,
                                                  const __bf16* __restrict__ Wcf,
                                                  const float* __restrict__ b1,
                                                  __bf16* __restrict__ Gall,
                                                  __bf16* __restrict__ Qall) {
    __shared__ __align__(16) __bf16 st[4][16][136];
    const int t = threadIdx.x, w = t >> 6, lane = t & 63;
    const int quad = lane >> 4, l16 = lane & 15;
    const int m0 = blockIdx.x * 16;

    bf16x8 a[2];
#pragma unroll
    for (int kk = 0; kk < 2; ++kk) {
        const float* ap = feat + (size_t)(m0 + l16) * 64 + kk * 32 + quad * 8;
        float4 a0 = *(const float4*)ap, a1 = *(const float4*)(ap + 4);
        bf16x8 v;
        v[0] = (__bf16)a0.x; v[1] = (__bf16)a0.y; v[2] = (__bf16)a0.z; v[3] = (__bf16)a0.w;
        v[4] = (__bf16)a1.x; v[5] = (__bf16)a1.y; v[6] = (__bf16)a1.z; v[7] = (__bf16)a1.w;
        a[kk] = v;
    }
    f32x4 acc[8];
#pragma unroll
    for (int nt = 0; nt < 8; ++nt) acc[nt] = (f32x4){0.f, 0.f, 0.f, 0.f};
#pragma unroll
    for (int kk = 0; kk < 2; ++kk)
#pragma unroll
        for (int nt = 0; nt < 8; ++nt) {
            bf16x8 bf = *(const bf16x8*)(Wcf + (size_t)(((w * 8 + nt) * 2 + kk) * 64 + lane) * 8);
            acc[nt] = __builtin_amdgcn_mfma_f32_16x16x32_bf16(a[kk], bf, acc[nt], 0, 0, 0);
        }

    const bool isQ = (w >= 2);
#pragma unroll
    for (int nt = 0; nt < 8; ++nt) {
        const int col = nt * 16 + l16;
        const float bias = isQ ? b1[(w - 2) * 128 + col] : 0.f;
#pragma unroll
        for (int r = 0; r < 4; ++r)
            st[w][quad * 4 + r][col] = (__bf16)(acc[nt][r] + bias);
    }
    __syncthreads();

    const int row = lane >> 2, c = lane & 3;
    const int m = m0 + row;
#pragma unroll
    for (int i = 0; i < 4; ++i) {
        const int col = c * 32 + i * 8;
        bf16x8 v = *(const bf16x8*)&st[w][row][col];
        if (!isQ) *(bf16x8*)(Gall + (size_t)m * H2 + w * 128 + col) = v;
        else      *(bf16x8*)(Qall + (size_t)m * H2 + (w - 2) * 128 + col) = v;
    }
}

// ---------------- fused_mlp7: out = mean_k gelu(gelu(G[idx]+Q) @ W2 + b2) -----------
// 256-thr blocks, 2 queries/wave, W2f staged in FOUR 16 KB quarters.
// Residency: LDS 16KB -> 10 blocks/CU; VGPR ~64 -> 8 waves/SIMD; net 8 blocks
// = 32 waves/CU (~2.7x round-9's 12) to hide G/Q gather latency + barrier drains.
__global__ __launch_bounds__(256, 4) void fused_mlp7(const __bf16* __restrict__ Gall,
                                                     const __bf16* __restrict__ Qall,
                                                     const int* __restrict__ knn_idx,
                                                     const __bf16* __restrict__ W2f,
                                                     const float* __restrict__ b2,
                                                     float* __restrict__ out) {
    __shared__ __align__(16) __bf16 w2s[8192];    // 16 KB: one quarter (2 kk8) of W2f
    const int t = threadIdx.x, w = t >> 6, lane = t & 63;
    const int quad = lane >> 4, l16 = lane & 15;

    const int wave_id = blockIdx.x * 4 + w;       // [0, 16384)
    const int q0 = wave_id * 2;                   // queries q0, q0+1
    const int b = q0 >> 10;
    const int nb0 = knn_idx[q0 * KNN + l16];
    const int nb1 = knn_idx[(q0 + 1) * KNN + l16];
    const __bf16* g0 = Gall + ((size_t)(b << 10) + nb0) * H2;
    const __bf16* g1 = Gall + ((size_t)(b << 10) + nb1) * H2;
    const __bf16* qq0 = Qall + (size_t)q0 * H2;
    const __bf16* qq1 = qq0 + H2;

    f32x4 acc[2][8];
#pragma unroll
    for (int tm = 0; tm < 2; ++tm)
#pragma unroll
        for (int nt = 0; nt < 8; ++nt) acc[tm][nt] = (f32x4){0.f, 0.f, 0.f, 0.f};

#pragma unroll
    for (int qtr = 0; qtr < 4; ++qtr) {
        if (qtr) __syncthreads();    // all waves done reading previous quarter
#pragma unroll
        for (int i = 0; i < 4; ++i) {
            bf16x8 v = *(const bf16x8*)(W2f + (size_t)(qtr * 8192 + i * 2048 + t * 8));
            *(bf16x8*)&w2s[i * 2048 + t * 8] = v;
        }
        __syncthreads();

#pragma unroll
        for (int kl = 0; kl < 2; ++kl) {
            const int ho = (qtr * 2 + kl) * 32 + quad * 8;
            bf16x8 gA = *(const bf16x8*)(g0 + ho);
            bf16x8 qA = *(const bf16x8*)(qq0 + ho);
            bf16x8 gB = *(const bf16x8*)(g1 + ho);
            bf16x8 qB = *(const bf16x8*)(qq1 + ho);
            bf16x8 a0, a1;
#pragma unroll
            for (int j = 0; j < 8; ++j) {
                a0[j] = (__bf16)gelu_fast((float)gA[j] + (float)qA[j]);
                a1[j] = (__bf16)gelu_fast((float)gB[j] + (float)qB[j]);
            }
            const __bf16* bb = &w2s[kl * 4096 + lane * 8];
#pragma unroll
            for (int nt = 0; nt < 8; ++nt) {
                bf16x8 bf = *(const bf16x8*)(bb + nt * 512);
                acc[0][nt] = __builtin_amdgcn_mfma_f32_16x16x32_bf16(a0, bf, acc[0][nt], 0, 0, 0);
                acc[1][nt] = __builtin_amdgcn_mfma_f32_16x16x32_bf16(a1, bf, acc[1][nt], 0, 0, 0);
            }
        }
    }

#pragma unroll
    for (int tm = 0; tm < 2; ++tm)
#pragma unroll
        for (int nt = 0; nt < 8; ++nt) {
            const float bias = b2[nt * 16 + l16];
            float s = 0.f;
#pragma unroll
            for (int r = 0; r < 4; ++r) s += gelu_fast(acc[tm][nt][r] + bias);
            s += __shfl_xor(s, 16, 64);
            s += __shfl_xor(s, 32, 64);
            if (quad == 0)
                out[(size_t)(q0 + tm) * PP + nt * 16 + l16] = s * 0.0625f;
        }
}

extern "C" void kernel_launch(void* const* d_in, const int* in_sizes, int n_in,
                              void* d_out, int out_size, void* d_ws, size_t ws_size,
                              hipStream_t stream) {
    const float* points   = (const float*)d_in[0];
    const float* features = (const float*)d_in[1];
    const float* W1 = (const float*)d_in[2];
    const float* b1 = (const float*)d_in[3];
    const float* W2 = (const float*)d_in[4];
    const float* b2 = (const float*)d_in[5];
    float* out = (float*)d_out;

    const size_t IDX_B  = (size_t)BB * NN * KNN * 4;   // 2 MB
    const size_t WCF_B  = 512 * 64 * 2;                // 64 KB
    const size_t W2F_B  = 256 * 128 * 2;               // 64 KB
    const size_t G_B    = (size_t)BB * NN * H2 * 2;    // 16 MB

    int* knn_idx = (int*)d_ws;
    char* p = (char*)d_ws + IDX_B;
    __bf16* Wcf  = (__bf16*)p;  p += WCF_B;
    __bf16* W2f  = (__bf16*)p;  p += W2F_B;
    __bf16* Gall = (__bf16*)p;  p += G_B;
    __bf16* Qall = (__bf16*)p;                         // 16 MB -> total ~34.1 MB

    knn_prep<<<4112, 512, 0, stream>>>(points, knn_idx, W1, W2, Wcf, W2f);
    gq_gemm<<<2048, 256, 0, stream>>>(features, Wcf, b1, Gall, Qall);
    fused_mlp7<<<4096, 256, 0, stream>>>(Gall, Qall, knn_idx, W2f, b2, out);
}